// Round 2
// baseline (1041.920 us; speedup 1.0000x reference)
//
#include <hip/hip_runtime.h>

typedef __attribute__((ext_vector_type(8))) short s16x8;
typedef __attribute__((ext_vector_type(8))) unsigned short u16x8;
typedef __attribute__((ext_vector_type(4))) float f32x4;

#define LN_EPS 1e-5f

__device__ inline float bf2f(unsigned short u) {
    union { unsigned int i; float f; } x; x.i = ((unsigned int)u) << 16; return x.f;
}
__device__ inline unsigned short f2bf(float f) {
    unsigned int u = __builtin_bit_cast(unsigned int, f);
    u += 0x7FFFu + ((u >> 16) & 1u);
    return (unsigned short)(u >> 16);
}

// ---------------------------------------------------------------------------
// Grouped GEMM:  C[m] = A[m](bf16) @ W[m](f32)^T  (+bias_scale*bias1+bias2)(+ReLU)
// A: bf16 ws tensor, rows x K, row stride lda, mode stride strideA_mode.
// W: f32 global, [N x K] row-major per mode.
// 64x64 tile, 4 waves (2x2), each wave 32x32 via 2x2 mfma_f32_16x16x32_bf16.
// rows multiple of 64; N arbitrary (guarded); K multiple of 32.
// ---------------------------------------------------------------------------
template<bool RELU, bool F32OUT>
__global__ __launch_bounds__(256) void gemm_bt_kernel(
    const unsigned short* __restrict__ A,
    const float* __restrict__ W,
    const float* __restrict__ bias1,
    const float* __restrict__ bias2,
    float bias_scale,
    void* __restrict__ Cv,
    int N, int K,
    size_t strideA_mode, size_t lda,
    size_t strideW_mode,
    size_t strideB_mode,
    size_t strideC_mode, size_t ldc)
{
    const int m = blockIdx.z;
    const int n0 = blockIdx.x * 64;
    const int r0 = blockIdx.y * 64;
    const unsigned short* Am = A + (size_t)m * strideA_mode;
    const float* Wm = W + (size_t)m * strideW_mode;

    __shared__ __align__(16) unsigned short As[64][40];
    __shared__ __align__(16) unsigned short Bs[64][40];

    const int tid = threadIdx.x;
    const int lane = tid & 63, wid = tid >> 6;
    const int wr = (wid >> 1) * 32, wc = (wid & 1) * 32;
    const int fr = lane & 15, ks = lane >> 4;
    const int lrow = tid >> 2, lslot = tid & 3;

    f32x4 acc[2][2];
#pragma unroll
    for (int i = 0; i < 2; ++i)
#pragma unroll
        for (int j = 0; j < 2; ++j)
#pragma unroll
            for (int r = 0; r < 4; ++r) acc[i][j][r] = 0.f;

    const int bcol = n0 + lrow;
    for (int k0 = 0; k0 < K; k0 += 32) {
        u16x8 av = *(const u16x8*)(Am + (size_t)(r0 + lrow) * lda + k0 + lslot * 8);
        u16x8 bv;
#pragma unroll
        for (int i = 0; i < 8; ++i) bv[i] = 0;
        if (bcol < N) {
            const float* wp = Wm + (size_t)bcol * K + k0 + lslot * 8;
            float4 w0 = *(const float4*)(wp);
            float4 w1 = *(const float4*)(wp + 4);
            bv[0] = f2bf(w0.x); bv[1] = f2bf(w0.y); bv[2] = f2bf(w0.z); bv[3] = f2bf(w0.w);
            bv[4] = f2bf(w1.x); bv[5] = f2bf(w1.y); bv[6] = f2bf(w1.z); bv[7] = f2bf(w1.w);
        }
        __syncthreads();
        *(u16x8*)(&As[lrow][lslot * 8]) = av;
        *(u16x8*)(&Bs[lrow][lslot * 8]) = bv;
        __syncthreads();
        s16x8 a0 = *(const s16x8*)(&As[wr + fr][ks * 8]);
        s16x8 a1 = *(const s16x8*)(&As[wr + 16 + fr][ks * 8]);
        s16x8 b0 = *(const s16x8*)(&Bs[wc + fr][ks * 8]);
        s16x8 b1 = *(const s16x8*)(&Bs[wc + 16 + fr][ks * 8]);
        acc[0][0] = __builtin_amdgcn_mfma_f32_16x16x32_bf16(a0, b0, acc[0][0], 0, 0, 0);
        acc[0][1] = __builtin_amdgcn_mfma_f32_16x16x32_bf16(a0, b1, acc[0][1], 0, 0, 0);
        acc[1][0] = __builtin_amdgcn_mfma_f32_16x16x32_bf16(a1, b0, acc[1][0], 0, 0, 0);
        acc[1][1] = __builtin_amdgcn_mfma_f32_16x16x32_bf16(a1, b1, acc[1][1], 0, 0, 0);
    }

#pragma unroll
    for (int mi = 0; mi < 2; ++mi)
#pragma unroll
        for (int ni = 0; ni < 2; ++ni) {
            const int col = n0 + wc + ni * 16 + fr;
            if (col < N) {
                float bsum = 0.f;
                if (bias1) bsum += bias_scale * bias1[(size_t)m * strideB_mode + col];
                if (bias2) bsum += bias2[(size_t)m * strideB_mode + col];
#pragma unroll
                for (int r = 0; r < 4; ++r) {
                    const int row = r0 + wr + mi * 16 + ks * 4 + r;
                    float v = acc[mi][ni][r] + bsum;
                    if (RELU) v = fmaxf(v, 0.f);
                    const size_t idx = (size_t)m * strideC_mode + (size_t)row * ldc + col;
                    if (F32OUT) ((float*)Cv)[idx] = v;
                    else ((unsigned short*)Cv)[idx] = f2bf(v);
                }
            }
        }
}

// ---------------------------------------------------------------------------
// Embedding: e[b,d] = mean_s emb[x[b,s], d]   (D=512, S=128), f32 in, bf16 out
// ---------------------------------------------------------------------------
__global__ __launch_bounds__(512) void embed_kernel(
    const int* __restrict__ x, const float* __restrict__ emb,
    unsigned short* __restrict__ e)
{
    const int b = blockIdx.x;
    __shared__ int xs[128];
    const int tid = threadIdx.x;
    if (tid < 128) xs[tid] = x[b * 128 + tid];
    __syncthreads();
    float s = 0.f;
    for (int i = 0; i < 128; ++i) s += emb[(size_t)xs[i] * 512 + tid];
    e[(size_t)b * 512 + tid] = f2bf(s * (1.f / 128.f));
}

// ---------------------------------------------------------------------------
// Row LayerNorm over D=512 (+opt ReLU), in-place safe. gamma/beta f32,
// selected by m = row % M.
// ---------------------------------------------------------------------------
template<bool RELU>
__global__ __launch_bounds__(256) void ln_kernel(
    const unsigned short* __restrict__ X,
    const float* __restrict__ G,
    const float* __restrict__ Bt,
    unsigned short* __restrict__ Y,
    int M)
{
    const int row = blockIdx.x;
    const int m = row % M;
    const unsigned short* xr = X + (size_t)row * 512;
    unsigned short* yr = Y + (size_t)row * 512;
    const int tid = threadIdx.x;
    const float x0 = bf2f(xr[tid]), x1 = bf2f(xr[tid + 256]);
    float s = x0 + x1, q = x0 * x0 + x1 * x1;
#pragma unroll
    for (int off = 32; off; off >>= 1) {
        s += __shfl_xor(s, off);
        q += __shfl_xor(q, off);
    }
    __shared__ float red[4][2];
    const int wid = tid >> 6, lane = tid & 63;
    if (lane == 0) { red[wid][0] = s; red[wid][1] = q; }
    __syncthreads();
    s = red[0][0] + red[1][0] + red[2][0] + red[3][0];
    q = red[0][1] + red[1][1] + red[2][1] + red[3][1];
    const float mu = s * (1.f / 512.f);
    const float var = q * (1.f / 512.f) - mu * mu;
    const float rstd = rsqrtf(var + LN_EPS);
    const float* g = G + (size_t)m * 512;
    const float* bt = Bt + (size_t)m * 512;
    float y0 = (x0 - mu) * rstd * g[tid] + bt[tid];
    float y1 = (x1 - mu) * rstd * g[tid + 256] + bt[tid + 256];
    if (RELU) { y0 = fmaxf(y0, 0.f); y1 = fmaxf(y1, 0.f); }
    yr[tid] = f2bf(y0);
    yr[tid + 256] = f2bf(y1);
}

// ---------------------------------------------------------------------------
// Attention: one block per (local_b, h). qkv chunk is bf16 [64,150,1536].
// K,V staged in LDS; 4 waves sweep q rows independently (wave-local sync only).
// ---------------------------------------------------------------------------
__global__ __launch_bounds__(256) void attn_kernel(
    const unsigned short* __restrict__ qkv, unsigned short* __restrict__ o_att,
    int b0)
{
    const int bl = blockIdx.x >> 3, h = blockIdx.x & 7;
    __shared__ __align__(16) unsigned short k_s[150][88];
    __shared__ __align__(16) unsigned short v_s[150][88];
    __shared__ float p_lds[4][152];
    const int tid = threadIdx.x, lane = tid & 63, wid = tid >> 6;
    const size_t base = (size_t)bl * 150 * 1536 + h * 64;

    for (int idx = tid; idx < 150 * 8; idx += 256) {
        const int r = idx >> 3, c = (idx & 7) * 8;
        *(u16x8*)(&k_s[r][c]) = *(const u16x8*)(qkv + base + (size_t)r * 1536 + 512 + c);
        *(u16x8*)(&v_s[r][c]) = *(const u16x8*)(qkv + base + (size_t)r * 1536 + 1024 + c);
    }
    __syncthreads();

    for (int qq = wid; qq < 150; qq += 4) {
        const unsigned short* qrow = qkv + base + (size_t)qq * 1536;
        u16x8 q8[8];
#pragma unroll
        for (int i = 0; i < 8; ++i) q8[i] = *(const u16x8*)(qrow + i * 8);
        float sc[3];
#pragma unroll
        for (int t = 0; t < 3; ++t) {
            const int kk = lane + t * 64;
            if (kk < 150) {
                float a = 0.f;
#pragma unroll
                for (int i = 0; i < 8; ++i) {
                    u16x8 k8 = *(const u16x8*)(&k_s[kk][i * 8]);
#pragma unroll
                    for (int j = 0; j < 8; ++j) a += bf2f(q8[i][j]) * bf2f(k8[j]);
                }
                sc[t] = a * 0.125f;
            } else sc[t] = -1e30f;
        }
        float mx = fmaxf(sc[0], fmaxf(sc[1], sc[2]));
#pragma unroll
        for (int off = 32; off; off >>= 1) mx = fmaxf(mx, __shfl_xor(mx, off));
        float e[3], sum = 0.f;
#pragma unroll
        for (int t = 0; t < 3; ++t) {
            e[t] = (lane + t * 64 < 150) ? __expf(sc[t] - mx) : 0.f;
            sum += e[t];
        }
#pragma unroll
        for (int off = 32; off; off >>= 1) sum += __shfl_xor(sum, off);
        const float inv = 1.f / sum;
#pragma unroll
        for (int t = 0; t < 3; ++t) {
            const int kk = lane + t * 64;
            if (kk < 150) p_lds[wid][kk] = e[t] * inv;
        }
        asm volatile("s_waitcnt lgkmcnt(0)" ::: "memory");
        __builtin_amdgcn_wave_barrier();
        float o = 0.f;
        for (int k = 0; k < 150; ++k) o = fmaf(p_lds[wid][k], bf2f(v_s[k][lane]), o);
        o_att[(size_t)((b0 + bl) * 150 + qq) * 512 + h * 64 + lane] = f2bf(o);
    }
}

// ---------------------------------------------------------------------------
// osum[b,d] = sum_m o_att[b,m,d]   (f32 accumulate)
// ---------------------------------------------------------------------------
__global__ __launch_bounds__(512) void osum_kernel(
    const unsigned short* __restrict__ o_att, unsigned short* __restrict__ osum)
{
    const int b = blockIdx.x, tid = threadIdx.x;
    float s = 0.f;
    const unsigned short* p = o_att + (size_t)b * 150 * 512 + tid;
    for (int mm = 0; mm < 150; ++mm) s += bf2f(p[(size_t)mm * 512]);
    osum[(size_t)b * 512 + tid] = f2bf(s);
}

// ---------------------------------------------------------------------------
extern "C" void kernel_launch(void* const* d_in, const int* in_sizes, int n_in,
                              void* d_out, int out_size, void* d_ws, size_t ws_size,
                              hipStream_t stream)
{
    (void)in_sizes; (void)n_in; (void)out_size; (void)ws_size;

    const int*   x          = (const int*)d_in[0];
    const float* emb        = (const float*)d_in[1];
    const float* W1         = (const float*)d_in[2];
    const float* b1         = (const float*)d_in[3];
    const float* ln1_g      = (const float*)d_in[4];
    const float* ln1_b      = (const float*)d_in[5];
    const float* W2         = (const float*)d_in[6];
    const float* b2         = (const float*)d_in[7];
    const float* dbias      = (const float*)d_in[8];
    const float* in_proj_w  = (const float*)d_in[9];
    const float* in_proj_b  = (const float*)d_in[10];
    const float* out_proj_w = (const float*)d_in[11];
    const float* out_proj_b = (const float*)d_in[12];
    const float* norm_g     = (const float*)d_in[13];
    const float* norm_b     = (const float*)d_in[14];
    const float* dec_w1     = (const float*)d_in[15];
    const float* dec_b1     = (const float*)d_in[16];
    const float* dec_w2     = (const float*)d_in[17];
    const float* dec_b2     = (const float*)d_in[18];

    char* ws = (char*)d_ws;
    unsigned short* e_bf  = (unsigned short*)(ws + 0x0);        // [256,512] bf16
    unsigned short* osum  = (unsigned short*)(ws + 0x40000);    // [256,512]
    unsigned short* att1  = (unsigned short*)(ws + 0x80000);    // [256,512]
    unsigned short* agg   = (unsigned short*)(ws + 0xC0000);    // [256,512]
    unsigned short* dec1  = (unsigned short*)(ws + 0x100000);   // [256,256]
    unsigned short* h1    = (unsigned short*)(ws + 0x200000);   // [B,M,D] 37.5MB (later o_att)
    unsigned short* mo    = (unsigned short*)(ws + 0x2800000);  // [B,M,D] 37.5MB
    unsigned short* qkvb  = (unsigned short*)(ws + 0x4E00000);  // [64,M,3D] 28.1MB chunk
    unsigned short* o_att = h1;                                  // alias: h1 dead after G2
    // total ws footprint: 0x4E00000 + 0x1C20000 = 0x6A20000 ≈ 111 MB

    // 1) embedding mean -> e [256,512]
    embed_kernel<<<256, 512, 0, stream>>>(x, emb, e_bf);

    // 2) G1: h1[b,m,:] = e[b,:] @ W1[m]^T + b1[m]
    gemm_bt_kernel<false, false><<<dim3(8, 4, 150), 256, 0, stream>>>(
        e_bf, W1, b1, nullptr, 1.f, h1,
        512, 512, (size_t)0, 512, (size_t)512 * 512, 512, 512, 76800);

    // 3) LN(ln1_g, ln1_b) + ReLU, in-place on h1
    ln_kernel<true><<<38400, 256, 0, stream>>>(h1, ln1_g, ln1_b, h1, 150);

    // 4) G2: mo[b,m,:] = h1[b,m,:] @ W2[m]^T + b2[m] + dbias[m]
    gemm_bt_kernel<false, false><<<dim3(8, 4, 150), 256, 0, stream>>>(
        h1, W2, b2, dbias, 1.f, mo,
        512, 512, (size_t)512, 76800, (size_t)512 * 512, 512, 512, 76800);

    // 5) per 64-batch chunk: qkv = mo @ in_proj_w^T + b, then attention
    for (int c = 0; c < 4; ++c) {
        gemm_bt_kernel<false, false><<<dim3(24, 150, 1), 256, 0, stream>>>(
            mo + (size_t)c * 64 * 76800, in_proj_w, in_proj_b, nullptr, 1.f, qkvb,
            1536, 512, (size_t)0, 512, (size_t)0, 0, 0, 1536);
        attn_kernel<<<512, 256, 0, stream>>>(qkvb, o_att, c * 64);
    }

    // 6) osum[b,:] = sum_m o_att[b,m,:]
    osum_kernel<<<256, 512, 0, stream>>>(o_att, osum);

    // 7) attended_sum = osum @ out_proj_w^T + 150*out_proj_b  (sum commutes w/ linear)
    gemm_bt_kernel<false, false><<<dim3(8, 4, 1), 256, 0, stream>>>(
        osum, out_proj_w, out_proj_b, nullptr, 150.f, att1,
        512, 512, (size_t)0, 512, (size_t)0, 0, 0, 512);

    // 8) agg = LN(attended_sum; norm_g, norm_b)
    ln_kernel<false><<<256, 256, 0, stream>>>(att1, norm_g, norm_b, agg, 1);

    // 9) dec1 = ReLU(agg @ dec_w1^T + dec_b1)   [256,256]
    gemm_bt_kernel<true, false><<<dim3(4, 4, 1), 256, 0, stream>>>(
        agg, dec_w1, dec_b1, nullptr, 1.f, dec1,
        256, 512, (size_t)0, 512, (size_t)0, 0, 0, 256);

    // 10) out = dec1 @ dec_w2^T + dec_b2   [256,10000]  (f32 out)
    gemm_bt_kernel<false, true><<<dim3(157, 4, 1), 256, 0, stream>>>(
        dec1, dec_w2, dec_b2, nullptr, 1.f, d_out,
        10000, 256, (size_t)0, 256, (size_t)0, 0, 0, 10000);
}

// Round 3
// 509.209 us; speedup vs baseline: 2.0462x; 2.0462x over previous
//
#include <hip/hip_runtime.h>

typedef __attribute__((ext_vector_type(8))) short s16x8;
typedef __attribute__((ext_vector_type(8))) unsigned short u16x8;
typedef __attribute__((ext_vector_type(4))) float f32x4;

#define LN_EPS 1e-5f

__device__ inline float bf2f(unsigned short u) {
    union { unsigned int i; float f; } x; x.i = ((unsigned int)u) << 16; return x.f;
}
__device__ inline unsigned short f2bf(float f) {
    unsigned int u = __builtin_bit_cast(unsigned int, f);
    u += 0x7FFFu + ((u >> 16) & 1u);
    return (unsigned short)(u >> 16);
}

// ---------------------------------------------------------------------------
// Grouped GEMM:  C[m] = A[m](bf16) @ W[m](f32)^T  (+bias_scale*bias1+bias2)(+ReLU)
// 64x64 tile, 4 waves (2x2), each wave 32x32 via 2x2 mfma_f32_16x16x32_bf16.
// ---------------------------------------------------------------------------
template<bool RELU, bool F32OUT>
__global__ __launch_bounds__(256) void gemm_bt_kernel(
    const unsigned short* __restrict__ A,
    const float* __restrict__ W,
    const float* __restrict__ bias1,
    const float* __restrict__ bias2,
    float bias_scale,
    void* __restrict__ Cv,
    int N, int K,
    size_t strideA_mode, size_t lda,
    size_t strideW_mode,
    size_t strideB_mode,
    size_t strideC_mode, size_t ldc)
{
    const int m = blockIdx.z;
    const int n0 = blockIdx.x * 64;
    const int r0 = blockIdx.y * 64;
    const unsigned short* Am = A + (size_t)m * strideA_mode;
    const float* Wm = W + (size_t)m * strideW_mode;

    __shared__ __align__(16) unsigned short As[64][40];
    __shared__ __align__(16) unsigned short Bs[64][40];

    const int tid = threadIdx.x;
    const int lane = tid & 63, wid = tid >> 6;
    const int wr = (wid >> 1) * 32, wc = (wid & 1) * 32;
    const int fr = lane & 15, ks = lane >> 4;
    const int lrow = tid >> 2, lslot = tid & 3;

    f32x4 acc[2][2];
#pragma unroll
    for (int i = 0; i < 2; ++i)
#pragma unroll
        for (int j = 0; j < 2; ++j)
#pragma unroll
            for (int r = 0; r < 4; ++r) acc[i][j][r] = 0.f;

    const int bcol = n0 + lrow;
    for (int k0 = 0; k0 < K; k0 += 32) {
        u16x8 av = *(const u16x8*)(Am + (size_t)(r0 + lrow) * lda + k0 + lslot * 8);
        u16x8 bv;
#pragma unroll
        for (int i = 0; i < 8; ++i) bv[i] = 0;
        if (bcol < N) {
            const float* wp = Wm + (size_t)bcol * K + k0 + lslot * 8;
            float4 w0 = *(const float4*)(wp);
            float4 w1 = *(const float4*)(wp + 4);
            bv[0] = f2bf(w0.x); bv[1] = f2bf(w0.y); bv[2] = f2bf(w0.z); bv[3] = f2bf(w0.w);
            bv[4] = f2bf(w1.x); bv[5] = f2bf(w1.y); bv[6] = f2bf(w1.z); bv[7] = f2bf(w1.w);
        }
        __syncthreads();
        *(u16x8*)(&As[lrow][lslot * 8]) = av;
        *(u16x8*)(&Bs[lrow][lslot * 8]) = bv;
        __syncthreads();
        s16x8 a0 = *(const s16x8*)(&As[wr + fr][ks * 8]);
        s16x8 a1 = *(const s16x8*)(&As[wr + 16 + fr][ks * 8]);
        s16x8 b0 = *(const s16x8*)(&Bs[wc + fr][ks * 8]);
        s16x8 b1 = *(const s16x8*)(&Bs[wc + 16 + fr][ks * 8]);
        acc[0][0] = __builtin_amdgcn_mfma_f32_16x16x32_bf16(a0, b0, acc[0][0], 0, 0, 0);
        acc[0][1] = __builtin_amdgcn_mfma_f32_16x16x32_bf16(a0, b1, acc[0][1], 0, 0, 0);
        acc[1][0] = __builtin_amdgcn_mfma_f32_16x16x32_bf16(a1, b0, acc[1][0], 0, 0, 0);
        acc[1][1] = __builtin_amdgcn_mfma_f32_16x16x32_bf16(a1, b1, acc[1][1], 0, 0, 0);
    }

#pragma unroll
    for (int mi = 0; mi < 2; ++mi)
#pragma unroll
        for (int ni = 0; ni < 2; ++ni) {
            const int col = n0 + wc + ni * 16 + fr;
            if (col < N) {
                float bsum = 0.f;
                if (bias1) bsum += bias_scale * bias1[(size_t)m * strideB_mode + col];
                if (bias2) bsum += bias2[(size_t)m * strideB_mode + col];
#pragma unroll
                for (int r = 0; r < 4; ++r) {
                    const int row = r0 + wr + mi * 16 + ks * 4 + r;
                    float v = acc[mi][ni][r] + bsum;
                    if (RELU) v = fmaxf(v, 0.f);
                    const size_t idx = (size_t)m * strideC_mode + (size_t)row * ldc + col;
                    if (F32OUT) ((float*)Cv)[idx] = v;
                    else ((unsigned short*)Cv)[idx] = f2bf(v);
                }
            }
        }
}

// ---------------------------------------------------------------------------
// Embedding: e[b,d] = mean_s emb[x[b,s], d]
// ---------------------------------------------------------------------------
__global__ __launch_bounds__(512) void embed_kernel(
    const int* __restrict__ x, const float* __restrict__ emb,
    unsigned short* __restrict__ e)
{
    const int b = blockIdx.x;
    __shared__ int xs[128];
    const int tid = threadIdx.x;
    if (tid < 128) xs[tid] = x[b * 128 + tid];
    __syncthreads();
    float s = 0.f;
    for (int i = 0; i < 128; ++i) s += emb[(size_t)xs[i] * 512 + tid];
    e[(size_t)b * 512 + tid] = f2bf(s * (1.f / 128.f));
}

// ---------------------------------------------------------------------------
// Row LayerNorm over D=512 (+opt ReLU), gamma/beta f32, m = row % M.
// ---------------------------------------------------------------------------
template<bool RELU>
__global__ __launch_bounds__(256) void ln_kernel(
    const unsigned short* __restrict__ X,
    const float* __restrict__ G,
    const float* __restrict__ Bt,
    unsigned short* __restrict__ Y,
    int M)
{
    const int row = blockIdx.x;
    const int m = row % M;
    const unsigned short* xr = X + (size_t)row * 512;
    unsigned short* yr = Y + (size_t)row * 512;
    const int tid = threadIdx.x;
    const float x0 = bf2f(xr[tid]), x1 = bf2f(xr[tid + 256]);
    float s = x0 + x1, q = x0 * x0 + x1 * x1;
#pragma unroll
    for (int off = 32; off; off >>= 1) {
        s += __shfl_xor(s, off);
        q += __shfl_xor(q, off);
    }
    __shared__ float red[4][2];
    const int wid = tid >> 6, lane = tid & 63;
    if (lane == 0) { red[wid][0] = s; red[wid][1] = q; }
    __syncthreads();
    s = red[0][0] + red[1][0] + red[2][0] + red[3][0];
    q = red[0][1] + red[1][1] + red[2][1] + red[3][1];
    const float mu = s * (1.f / 512.f);
    const float var = q * (1.f / 512.f) - mu * mu;
    const float rstd = rsqrtf(var + LN_EPS);
    const float* g = G + (size_t)m * 512;
    const float* bt = Bt + (size_t)m * 512;
    float y0 = (x0 - mu) * rstd * g[tid] + bt[tid];
    float y1 = (x1 - mu) * rstd * g[tid + 256] + bt[tid + 256];
    if (RELU) { y0 = fmaxf(y0, 0.f); y1 = fmaxf(y1, 0.f); }
    yr[tid] = f2bf(y0);
    yr[tid + 256] = f2bf(y1);
}

// ---------------------------------------------------------------------------
// MFMA attention: one block per (local_b, h). M=150 padded to 160.
// S = mfma(Q,K) (X@Y^T), in-register softmax, P->LDS (wave-private),
// O = mfma(P, V^T). Normalization deferred to O epilogue.
// ---------------------------------------------------------------------------
#define KP 72    // K LDS row pitch (elems)
#define VP 168   // V^T / P LDS row pitch (elems)
__global__ __launch_bounds__(256) void attn_mfma_kernel(
    const unsigned short* __restrict__ qkv, unsigned short* __restrict__ o_att,
    int b0)
{
    const int bl = blockIdx.x >> 3, h = blockIdx.x & 7;
    __shared__ __align__(16) unsigned short k_s[160 * KP];
    __shared__ __align__(16) unsigned short v_t[64 * VP];
    __shared__ __align__(16) unsigned short p_s[4][16 * VP];
    const int tid = threadIdx.x, lane = tid & 63, wid = tid >> 6;
    const int fr = lane & 15, ks = lane >> 4;
    const size_t base = (size_t)bl * (150 * 1536) + h * 64;

    // stage K [160][KP], rows >=150 zeroed (coalesced: r = idx>>3)
    for (int idx = tid; idx < 160 * 8; idx += 256) {
        const int r = idx >> 3, c8 = (idx & 7) * 8;
        u16x8 v;
        if (r < 150) v = *(const u16x8*)(qkv + base + (size_t)r * 1536 + 512 + c8);
        else {
#pragma unroll
            for (int j = 0; j < 8; ++j) v[j] = 0;
        }
        *(u16x8*)(&k_s[r * KP + c8]) = v;
    }
    // stage V^T: v_t[d][r] (distinct-r mapping keeps LDS writes conflict-free)
    for (int idx = tid; idx < 160 * 8; idx += 256) {
        const int c8 = idx / 160, r = idx - c8 * 160;
        u16x8 v;
        if (r < 150) v = *(const u16x8*)(qkv + base + (size_t)r * 1536 + 1024 + c8 * 8);
        else {
#pragma unroll
            for (int j = 0; j < 8; ++j) v[j] = 0;
        }
#pragma unroll
        for (int j = 0; j < 8; ++j) v_t[(c8 * 8 + j) * VP + r] = v[j];
    }
    __syncthreads();

    unsigned short* pw = &p_s[wid][0];

    for (int qt = wid; qt < 10; qt += 4) {
        // Q A-frags direct from global (row clamped; dup rows discarded at store)
        const int qr = (qt * 16 + fr < 150) ? qt * 16 + fr : 149;
        const unsigned short* qp = qkv + base + (size_t)qr * 1536;
        s16x8 qa0 = *(const s16x8*)(qp + ks * 8);
        s16x8 qa1 = *(const s16x8*)(qp + 32 + ks * 8);

        // S row-block: 10 k-tiles
        f32x4 acc[10];
#pragma unroll
        for (int t = 0; t < 10; ++t)
#pragma unroll
            for (int r = 0; r < 4; ++r) acc[t][r] = 0.f;
#pragma unroll
        for (int t = 0; t < 10; ++t) {
            s16x8 kb0 = *(const s16x8*)(&k_s[(t * 16 + fr) * KP + ks * 8]);
            s16x8 kb1 = *(const s16x8*)(&k_s[(t * 16 + fr) * KP + 32 + ks * 8]);
            acc[t] = __builtin_amdgcn_mfma_f32_16x16x32_bf16(qa0, kb0, acc[t], 0, 0, 0);
            acc[t] = __builtin_amdgcn_mfma_f32_16x16x32_bf16(qa1, kb1, acc[t], 0, 0, 0);
        }

        // softmax: row q = qt*16 + ks*4 + i ; col k = t*16 + fr
        const bool v9 = (fr < 6);  // tile 9 valid cols: 144..149
        float inv[4];
#pragma unroll
        for (int i = 0; i < 4; ++i) {
            float m = -1e30f;
#pragma unroll
            for (int t = 0; t < 9; ++t) m = fmaxf(m, acc[t][i]);
            if (v9) m = fmaxf(m, acc[9][i]);
#pragma unroll
            for (int off = 1; off < 16; off <<= 1) m = fmaxf(m, __shfl_xor(m, off));
            float s = 0.f;
#pragma unroll
            for (int t = 0; t < 10; ++t) {
                float e = 0.f;
                if (t < 9 || v9) e = __expf(0.125f * (acc[t][i] - m));
                s += e;
                pw[(ks * 4 + i) * VP + t * 16 + fr] = f2bf(e);
            }
#pragma unroll
            for (int off = 1; off < 16; off <<= 1) s += __shfl_xor(s, off);
            inv[i] = 1.f / s;
        }

        // PV: O[16][64] = P[16][160] @ V[160][64]
        f32x4 o[4];
#pragma unroll
        for (int dt = 0; dt < 4; ++dt)
#pragma unroll
            for (int r = 0; r < 4; ++r) o[dt][r] = 0.f;
#pragma unroll
        for (int kc = 0; kc < 5; ++kc) {
            s16x8 pa = *(const s16x8*)(&pw[fr * VP + kc * 32 + ks * 8]);
#pragma unroll
            for (int dt = 0; dt < 4; ++dt) {
                s16x8 vb = *(const s16x8*)(&v_t[(dt * 16 + fr) * VP + kc * 32 + ks * 8]);
                o[dt] = __builtin_amdgcn_mfma_f32_16x16x32_bf16(pa, vb, o[dt], 0, 0, 0);
            }
        }

        // store O rows (normalize here)
#pragma unroll
        for (int dt = 0; dt < 4; ++dt) {
            const int d = h * 64 + dt * 16 + fr;
#pragma unroll
            for (int i = 0; i < 4; ++i) {
                const int q = qt * 16 + ks * 4 + i;
                if (q < 150)
                    o_att[((size_t)((b0 + bl) * 150 + q)) * 512 + d] = f2bf(o[dt][i] * inv[i]);
            }
        }
    }
}

// ---------------------------------------------------------------------------
// osum[b,d] = sum_m o_att[b,m,d]
// ---------------------------------------------------------------------------
__global__ __launch_bounds__(512) void osum_kernel(
    const unsigned short* __restrict__ o_att, unsigned short* __restrict__ osum)
{
    const int b = blockIdx.x, tid = threadIdx.x;
    float s = 0.f;
    const unsigned short* p = o_att + (size_t)b * 150 * 512 + tid;
    for (int mm = 0; mm < 150; ++mm) s += bf2f(p[(size_t)mm * 512]);
    osum[(size_t)b * 512 + tid] = f2bf(s);
}

// ---------------------------------------------------------------------------
extern "C" void kernel_launch(void* const* d_in, const int* in_sizes, int n_in,
                              void* d_out, int out_size, void* d_ws, size_t ws_size,
                              hipStream_t stream)
{
    (void)in_sizes; (void)n_in; (void)out_size; (void)ws_size;

    const int*   x          = (const int*)d_in[0];
    const float* emb        = (const float*)d_in[1];
    const float* W1         = (const float*)d_in[2];
    const float* b1         = (const float*)d_in[3];
    const float* ln1_g      = (const float*)d_in[4];
    const float* ln1_b      = (const float*)d_in[5];
    const float* W2         = (const float*)d_in[6];
    const float* b2         = (const float*)d_in[7];
    const float* dbias      = (const float*)d_in[8];
    const float* in_proj_w  = (const float*)d_in[9];
    const float* in_proj_b  = (const float*)d_in[10];
    const float* out_proj_w = (const float*)d_in[11];
    const float* out_proj_b = (const float*)d_in[12];
    const float* norm_g     = (const float*)d_in[13];
    const float* norm_b     = (const float*)d_in[14];
    const float* dec_w1     = (const float*)d_in[15];
    const float* dec_b1     = (const float*)d_in[16];
    const float* dec_w2     = (const float*)d_in[17];
    const float* dec_b2     = (const float*)d_in[18];

    char* ws = (char*)d_ws;
    unsigned short* e_bf  = (unsigned short*)(ws + 0x0);        // [256,512] bf16
    unsigned short* osum  = (unsigned short*)(ws + 0x40000);    // [256,512]
    unsigned short* att1  = (unsigned short*)(ws + 0x80000);    // [256,512]
    unsigned short* agg   = (unsigned short*)(ws + 0xC0000);    // [256,512]
    unsigned short* dec1  = (unsigned short*)(ws + 0x100000);   // [256,256]
    unsigned short* h1    = (unsigned short*)(ws + 0x200000);   // [B,M,D] 37.5MB (later o_att)
    unsigned short* mo    = (unsigned short*)(ws + 0x2800000);  // [B,M,D] 37.5MB
    unsigned short* qkvb  = (unsigned short*)(ws + 0x4E00000);  // [64,M,3D] 28.1MB chunk
    unsigned short* o_att = h1;                                  // alias: h1 dead after G2

    // 1) embedding mean -> e [256,512]
    embed_kernel<<<256, 512, 0, stream>>>(x, emb, e_bf);

    // 2) G1: h1[b,m,:] = e[b,:] @ W1[m]^T + b1[m]
    gemm_bt_kernel<false, false><<<dim3(8, 4, 150), 256, 0, stream>>>(
        e_bf, W1, b1, nullptr, 1.f, h1,
        512, 512, (size_t)0, 512, (size_t)512 * 512, 512, 512, 76800);

    // 3) LN(ln1_g, ln1_b) + ReLU, in-place on h1
    ln_kernel<true><<<38400, 256, 0, stream>>>(h1, ln1_g, ln1_b, h1, 150);

    // 4) G2: mo[b,m,:] = h1[b,m,:] @ W2[m]^T + b2[m] + dbias[m]
    gemm_bt_kernel<false, false><<<dim3(8, 4, 150), 256, 0, stream>>>(
        h1, W2, b2, dbias, 1.f, mo,
        512, 512, (size_t)512, 76800, (size_t)512 * 512, 512, 512, 76800);

    // 5) per 64-batch chunk: qkv = mo @ in_proj_w^T + b, then attention
    for (int c = 0; c < 4; ++c) {
        gemm_bt_kernel<false, false><<<dim3(24, 150, 1), 256, 0, stream>>>(
            mo + (size_t)c * 64 * 76800, in_proj_w, in_proj_b, nullptr, 1.f, qkvb,
            1536, 512, (size_t)0, 512, (size_t)0, 0, 0, 1536);
        attn_mfma_kernel<<<512, 256, 0, stream>>>(qkvb, o_att, c * 64);
    }

    // 6) osum[b,:] = sum_m o_att[b,m,:]
    osum_kernel<<<256, 512, 0, stream>>>(o_att, osum);

    // 7) attended_sum = osum @ out_proj_w^T + 150*out_proj_b
    gemm_bt_kernel<false, false><<<dim3(8, 4, 1), 256, 0, stream>>>(
        osum, out_proj_w, out_proj_b, nullptr, 150.f, att1,
        512, 512, (size_t)0, 512, (size_t)0, 0, 0, 512);

    // 8) agg = LN(attended_sum; norm_g, norm_b)
    ln_kernel<false><<<256, 256, 0, stream>>>(att1, norm_g, norm_b, agg, 1);

    // 9) dec1 = ReLU(agg @ dec_w1^T + dec_b1)   [256,256]
    gemm_bt_kernel<true, false><<<dim3(4, 4, 1), 256, 0, stream>>>(
        agg, dec_w1, dec_b1, nullptr, 1.f, dec1,
        256, 512, (size_t)0, 512, (size_t)0, 0, 0, 256);

    // 10) out = dec1 @ dec_w2^T + dec_b2   [256,10000]  (f32 out)
    gemm_bt_kernel<false, true><<<dim3(157, 4, 1), 256, 0, stream>>>(
        dec1, dec_w2, dec_b2, nullptr, 1.f, d_out,
        10000, 256, (size_t)0, 256, (size_t)0, 0, 0, 10000);
}

// Round 4
// 463.465 us; speedup vs baseline: 2.2481x; 1.0987x over previous
//
#include <hip/hip_runtime.h>

typedef __attribute__((ext_vector_type(8))) short s16x8;
typedef __attribute__((ext_vector_type(8))) unsigned short u16x8;
typedef __attribute__((ext_vector_type(4))) float f32x4;

#define LN_EPS 1e-5f

__device__ inline float bf2f(unsigned short u) {
    union { unsigned int i; float f; } x; x.i = ((unsigned int)u) << 16; return x.f;
}
__device__ inline unsigned short f2bf(float f) {
    unsigned int u = __builtin_bit_cast(unsigned int, f);
    u += 0x7FFFu + ((u >> 16) & 1u);
    return (unsigned short)(u >> 16);
}

// ---------------------------------------------------------------------------
// Big-tile grouped GEMM: C[z] = A[z](bf16) @ W[z](f32)^T (+bias) (+ReLU)
// Tile 256(M, full) x 128(N), BK=64, K%64==0, N%128==0.
// 512 threads = 8 waves (4 row-groups x 2 col-groups), wave = 64x64 via
// 4x4 frags of mfma_f32_16x16x32_bf16. Double-buffered LDS, issue-early/
// write-late staging (T14), XOR-swizzled LDS (T2): phys = row*128 +
// (colbyte ^ ((row&7)<<4)).
// ---------------------------------------------------------------------------
template<bool RELU>
__global__ __launch_bounds__(512) void gemm256_kernel(
    const unsigned short* __restrict__ A,
    const float* __restrict__ W,
    const float* __restrict__ bias1,
    const float* __restrict__ bias2,
    float bias_scale,
    unsigned short* __restrict__ C,
    int K, int rows_total,
    size_t strideA_mode, size_t lda,
    size_t strideW_mode, size_t strideB_mode,
    size_t strideC_mode, size_t ldc)
{
    const int z = blockIdx.y;
    const int n0 = blockIdx.x * 128;
    const int valid = min(256, rows_total - z * 256);

    // LDS: per buffer A[256][128B] then B[128][128B]
    __shared__ __align__(16) unsigned char smem[2][49152];

    const int tid = threadIdx.x;
    const int lane = tid & 63, wid = tid >> 6;
    const int wrow = (wid >> 1) * 64, wcol = (wid & 1) * 64;
    const int fr = lane & 15, ks = lane >> 4;

    // staging coords
    const int ar = tid >> 1, ah = tid & 1;          // A: row, 32-col half
    const int arc = min(ar, valid - 1);
    const int br = tid >> 2, bq = tid & 3;          // B: row (=out col), 16-col quarter
    const unsigned short* Ap = A + (size_t)z * strideA_mode + (size_t)arc * lda + ah * 32;
    const float* Wp = W + (size_t)z * strideW_mode + (size_t)(n0 + br) * K + bq * 16;

    f32x4 acc[4][4];
#pragma unroll
    for (int i = 0; i < 4; ++i)
#pragma unroll
        for (int j = 0; j < 4; ++j)
#pragma unroll
            for (int r = 0; r < 4; ++r) acc[i][j][r] = 0.f;

    u16x8 areg[4];
    float4 wreg[4];
    const int nsteps = K >> 6;
    int cur = 0;

    // ---- staging helpers (lambdas keep regs in scope) ----
    auto issue = [&](int k0) {
#pragma unroll
        for (int i = 0; i < 4; ++i) areg[i] = *(const u16x8*)(Ap + k0 + i * 8);
#pragma unroll
        for (int i = 0; i < 4; ++i) wreg[i] = *(const float4*)(Wp + k0 + i * 4);
    };
    auto write_lds = [&](int buf) {
        unsigned char* Ab = &smem[buf][0];
        unsigned char* Bb = &smem[buf][32768];
#pragma unroll
        for (int i = 0; i < 4; ++i) {
            const int slot = ah * 4 + i;
            *(u16x8*)(Ab + ar * 128 + ((slot * 16) ^ ((ar & 7) << 4))) = areg[i];
        }
        u16x8 c0, c1;
        c0[0] = f2bf(wreg[0].x); c0[1] = f2bf(wreg[0].y); c0[2] = f2bf(wreg[0].z); c0[3] = f2bf(wreg[0].w);
        c0[4] = f2bf(wreg[1].x); c0[5] = f2bf(wreg[1].y); c0[6] = f2bf(wreg[1].z); c0[7] = f2bf(wreg[1].w);
        c1[0] = f2bf(wreg[2].x); c1[1] = f2bf(wreg[2].y); c1[2] = f2bf(wreg[2].z); c1[3] = f2bf(wreg[2].w);
        c1[4] = f2bf(wreg[3].x); c1[5] = f2bf(wreg[3].y); c1[6] = f2bf(wreg[3].z); c1[7] = f2bf(wreg[3].w);
        *(u16x8*)(Bb + br * 128 + (((bq * 2 + 0) * 16) ^ ((br & 7) << 4))) = c0;
        *(u16x8*)(Bb + br * 128 + (((bq * 2 + 1) * 16) ^ ((br & 7) << 4))) = c1;
    };

    // ---- prologue ----
    issue(0);
    write_lds(cur);
    __syncthreads();

    // ---- main loop ----
    for (int t = 0; t < nsteps; ++t) {
        const bool more = (t + 1 < nsteps);
        if (more) issue((t + 1) * 64);

        const unsigned char* Ab = &smem[cur][0];
        const unsigned char* Bb = &smem[cur][32768];
#pragma unroll
        for (int kk = 0; kk < 2; ++kk) {
            const int kb = ks * 16 + kk * 64;   // colbyte of this k-slot
            s16x8 af[4], bf_[4];
#pragma unroll
            for (int mi = 0; mi < 4; ++mi) {
                const int r = wrow + mi * 16 + fr;
                af[mi] = *(const s16x8*)(Ab + r * 128 + (kb ^ ((r & 7) << 4)));
            }
#pragma unroll
            for (int ni = 0; ni < 4; ++ni) {
                const int r = wcol + ni * 16 + fr;
                bf_[ni] = *(const s16x8*)(Bb + r * 128 + (kb ^ ((r & 7) << 4)));
            }
#pragma unroll
            for (int mi = 0; mi < 4; ++mi)
#pragma unroll
                for (int ni = 0; ni < 4; ++ni)
                    acc[mi][ni] = __builtin_amdgcn_mfma_f32_16x16x32_bf16(af[mi], bf_[ni], acc[mi][ni], 0, 0, 0);
        }

        if (more) write_lds(cur ^ 1);
        __syncthreads();
        cur ^= 1;
    }

    // ---- epilogue ----
#pragma unroll
    for (int ni = 0; ni < 4; ++ni) {
        const int col = n0 + wcol + ni * 16 + fr;
        float bsum = 0.f;
        if (bias1) bsum += bias_scale * bias1[(size_t)z * strideB_mode + col];
        if (bias2) bsum += bias2[(size_t)z * strideB_mode + col];
#pragma unroll
        for (int mi = 0; mi < 4; ++mi) {
#pragma unroll
            for (int r = 0; r < 4; ++r) {
                const int rl = wrow + mi * 16 + ks * 4 + r;
                if (rl < valid) {
                    float v = acc[mi][ni][r] + bsum;
                    if (RELU) v = fmaxf(v, 0.f);
                    C[(size_t)z * strideC_mode + (size_t)rl * ldc + col] = f2bf(v);
                }
            }
        }
    }
}

// ---------------------------------------------------------------------------
// Legacy 64x64 GEMM (kept only for the final [256,10000] K=256 f32-out GEMM)
// ---------------------------------------------------------------------------
template<bool RELU, bool F32OUT>
__global__ __launch_bounds__(256) void gemm_bt_kernel(
    const unsigned short* __restrict__ A,
    const float* __restrict__ W,
    const float* __restrict__ bias1,
    const float* __restrict__ bias2,
    float bias_scale,
    void* __restrict__ Cv,
    int N, int K,
    size_t strideA_mode, size_t lda,
    size_t strideW_mode,
    size_t strideB_mode,
    size_t strideC_mode, size_t ldc)
{
    const int m = blockIdx.z;
    const int n0 = blockIdx.x * 64;
    const int r0 = blockIdx.y * 64;
    const unsigned short* Am = A + (size_t)m * strideA_mode;
    const float* Wm = W + (size_t)m * strideW_mode;

    __shared__ __align__(16) unsigned short As[64][40];
    __shared__ __align__(16) unsigned short Bs[64][40];

    const int tid = threadIdx.x;
    const int lane = tid & 63, wid = tid >> 6;
    const int wr = (wid >> 1) * 32, wc = (wid & 1) * 32;
    const int fr = lane & 15, ks = lane >> 4;
    const int lrow = tid >> 2, lslot = tid & 3;

    f32x4 acc[2][2];
#pragma unroll
    for (int i = 0; i < 2; ++i)
#pragma unroll
        for (int j = 0; j < 2; ++j)
#pragma unroll
            for (int r = 0; r < 4; ++r) acc[i][j][r] = 0.f;

    const int bcol = n0 + lrow;
    for (int k0 = 0; k0 < K; k0 += 32) {
        u16x8 av = *(const u16x8*)(Am + (size_t)(r0 + lrow) * lda + k0 + lslot * 8);
        u16x8 bv;
#pragma unroll
        for (int i = 0; i < 8; ++i) bv[i] = 0;
        if (bcol < N) {
            const float* wp = Wm + (size_t)bcol * K + k0 + lslot * 8;
            float4 w0 = *(const float4*)(wp);
            float4 w1 = *(const float4*)(wp + 4);
            bv[0] = f2bf(w0.x); bv[1] = f2bf(w0.y); bv[2] = f2bf(w0.z); bv[3] = f2bf(w0.w);
            bv[4] = f2bf(w1.x); bv[5] = f2bf(w1.y); bv[6] = f2bf(w1.z); bv[7] = f2bf(w1.w);
        }
        __syncthreads();
        *(u16x8*)(&As[lrow][lslot * 8]) = av;
        *(u16x8*)(&Bs[lrow][lslot * 8]) = bv;
        __syncthreads();
        s16x8 a0 = *(const s16x8*)(&As[wr + fr][ks * 8]);
        s16x8 a1 = *(const s16x8*)(&As[wr + 16 + fr][ks * 8]);
        s16x8 b0 = *(const s16x8*)(&Bs[wc + fr][ks * 8]);
        s16x8 b1 = *(const s16x8*)(&Bs[wc + 16 + fr][ks * 8]);
        acc[0][0] = __builtin_amdgcn_mfma_f32_16x16x32_bf16(a0, b0, acc[0][0], 0, 0, 0);
        acc[0][1] = __builtin_amdgcn_mfma_f32_16x16x32_bf16(a0, b1, acc[0][1], 0, 0, 0);
        acc[1][0] = __builtin_amdgcn_mfma_f32_16x16x32_bf16(a1, b0, acc[1][0], 0, 0, 0);
        acc[1][1] = __builtin_amdgcn_mfma_f32_16x16x32_bf16(a1, b1, acc[1][1], 0, 0, 0);
    }

#pragma unroll
    for (int mi = 0; mi < 2; ++mi)
#pragma unroll
        for (int ni = 0; ni < 2; ++ni) {
            const int col = n0 + wc + ni * 16 + fr;
            if (col < N) {
                float bsum = 0.f;
                if (bias1) bsum += bias_scale * bias1[(size_t)m * strideB_mode + col];
                if (bias2) bsum += bias2[(size_t)m * strideB_mode + col];
#pragma unroll
                for (int r = 0; r < 4; ++r) {
                    const int row = r0 + wr + mi * 16 + ks * 4 + r;
                    float v = acc[mi][ni][r] + bsum;
                    if (RELU) v = fmaxf(v, 0.f);
                    const size_t idx = (size_t)m * strideC_mode + (size_t)row * ldc + col;
                    if (F32OUT) ((float*)Cv)[idx] = v;
                    else ((unsigned short*)Cv)[idx] = f2bf(v);
                }
            }
        }
}

// ---------------------------------------------------------------------------
// Embedding: e[b,d] = mean_s emb[x[b,s], d]
// ---------------------------------------------------------------------------
__global__ __launch_bounds__(512) void embed_kernel(
    const int* __restrict__ x, const float* __restrict__ emb,
    unsigned short* __restrict__ e)
{
    const int b = blockIdx.x;
    __shared__ int xs[128];
    const int tid = threadIdx.x;
    if (tid < 128) xs[tid] = x[b * 128 + tid];
    __syncthreads();
    float s = 0.f;
    for (int i = 0; i < 128; ++i) s += emb[(size_t)xs[i] * 512 + tid];
    e[(size_t)b * 512 + tid] = f2bf(s * (1.f / 128.f));
}

// ---------------------------------------------------------------------------
// Row LayerNorm over D=512 (+opt ReLU), gamma/beta f32, m = row % M.
// ---------------------------------------------------------------------------
template<bool RELU>
__global__ __launch_bounds__(256) void ln_kernel(
    const unsigned short* __restrict__ X,
    const float* __restrict__ G,
    const float* __restrict__ Bt,
    unsigned short* __restrict__ Y,
    int M)
{
    const int row = blockIdx.x;
    const int m = row % M;
    const unsigned short* xr = X + (size_t)row * 512;
    unsigned short* yr = Y + (size_t)row * 512;
    const int tid = threadIdx.x;
    const float x0 = bf2f(xr[tid]), x1 = bf2f(xr[tid + 256]);
    float s = x0 + x1, q = x0 * x0 + x1 * x1;
#pragma unroll
    for (int off = 32; off; off >>= 1) {
        s += __shfl_xor(s, off);
        q += __shfl_xor(q, off);
    }
    __shared__ float red[4][2];
    const int wid = tid >> 6, lane = tid & 63;
    if (lane == 0) { red[wid][0] = s; red[wid][1] = q; }
    __syncthreads();
    s = red[0][0] + red[1][0] + red[2][0] + red[3][0];
    q = red[0][1] + red[1][1] + red[2][1] + red[3][1];
    const float mu = s * (1.f / 512.f);
    const float var = q * (1.f / 512.f) - mu * mu;
    const float rstd = rsqrtf(var + LN_EPS);
    const float* g = G + (size_t)m * 512;
    const float* bt = Bt + (size_t)m * 512;
    float y0 = (x0 - mu) * rstd * g[tid] + bt[tid];
    float y1 = (x1 - mu) * rstd * g[tid + 256] + bt[tid + 256];
    if (RELU) { y0 = fmaxf(y0, 0.f); y1 = fmaxf(y1, 0.f); }
    yr[tid] = f2bf(y0);
    yr[tid + 256] = f2bf(y1);
}

// ---------------------------------------------------------------------------
// MFMA attention (unchanged from round 3): one block per (local_b, h).
// ---------------------------------------------------------------------------
#define KP 72
#define VP 168
__global__ __launch_bounds__(256) void attn_mfma_kernel(
    const unsigned short* __restrict__ qkv, unsigned short* __restrict__ o_att,
    int b0)
{
    const int bl = blockIdx.x >> 3, h = blockIdx.x & 7;
    __shared__ __align__(16) unsigned short k_s[160 * KP];
    __shared__ __align__(16) unsigned short v_t[64 * VP];
    __shared__ __align__(16) unsigned short p_s[4][16 * VP];
    const int tid = threadIdx.x, lane = tid & 63, wid = tid >> 6;
    const int fr = lane & 15, ks = lane >> 4;
    const size_t base = (size_t)bl * (150 * 1536) + h * 64;

    for (int idx = tid; idx < 160 * 8; idx += 256) {
        const int r = idx >> 3, c8 = (idx & 7) * 8;
        u16x8 v;
        if (r < 150) v = *(const u16x8*)(qkv + base + (size_t)r * 1536 + 512 + c8);
        else {
#pragma unroll
            for (int j = 0; j < 8; ++j) v[j] = 0;
        }
        *(u16x8*)(&k_s[r * KP + c8]) = v;
    }
    for (int idx = tid; idx < 160 * 8; idx += 256) {
        const int c8 = idx / 160, r = idx - c8 * 160;
        u16x8 v;
        if (r < 150) v = *(const u16x8*)(qkv + base + (size_t)r * 1536 + 1024 + c8 * 8);
        else {
#pragma unroll
            for (int j = 0; j < 8; ++j) v[j] = 0;
        }
#pragma unroll
        for (int j = 0; j < 8; ++j) v_t[(c8 * 8 + j) * VP + r] = v[j];
    }
    __syncthreads();

    unsigned short* pw = &p_s[wid][0];

    for (int qt = wid; qt < 10; qt += 4) {
        const int qr = (qt * 16 + fr < 150) ? qt * 16 + fr : 149;
        const unsigned short* qp = qkv + base + (size_t)qr * 1536;
        s16x8 qa0 = *(const s16x8*)(qp + ks * 8);
        s16x8 qa1 = *(const s16x8*)(qp + 32 + ks * 8);

        f32x4 acc[10];
#pragma unroll
        for (int t = 0; t < 10; ++t)
#pragma unroll
            for (int r = 0; r < 4; ++r) acc[t][r] = 0.f;
#pragma unroll
        for (int t = 0; t < 10; ++t) {
            s16x8 kb0 = *(const s16x8*)(&k_s[(t * 16 + fr) * KP + ks * 8]);
            s16x8 kb1 = *(const s16x8*)(&k_s[(t * 16 + fr) * KP + 32 + ks * 8]);
            acc[t] = __builtin_amdgcn_mfma_f32_16x16x32_bf16(qa0, kb0, acc[t], 0, 0, 0);
            acc[t] = __builtin_amdgcn_mfma_f32_16x16x32_bf16(qa1, kb1, acc[t], 0, 0, 0);
        }

        const bool v9 = (fr < 6);
        float inv[4];
#pragma unroll
        for (int i = 0; i < 4; ++i) {
            float m = -1e30f;
#pragma unroll
            for (int t = 0; t < 9; ++t) m = fmaxf(m, acc[t][i]);
            if (v9) m = fmaxf(m, acc[9][i]);
#pragma unroll
            for (int off = 1; off < 16; off <<= 1) m = fmaxf(m, __shfl_xor(m, off));
            float s = 0.f;
#pragma unroll
            for (int t = 0; t < 10; ++t) {
                float e = 0.f;
                if (t < 9 || v9) e = __expf(0.125f * (acc[t][i] - m));
                s += e;
                pw[(ks * 4 + i) * VP + t * 16 + fr] = f2bf(e);
            }
#pragma unroll
            for (int off = 1; off < 16; off <<= 1) s += __shfl_xor(s, off);
            inv[i] = 1.f / s;
        }

        f32x4 o[4];
#pragma unroll
        for (int dt = 0; dt < 4; ++dt)
#pragma unroll
            for (int r = 0; r < 4; ++r) o[dt][r] = 0.f;
#pragma unroll
        for (int kc = 0; kc < 5; ++kc) {
            s16x8 pa = *(const s16x8*)(&pw[fr * VP + kc * 32 + ks * 8]);
#pragma unroll
            for (int dt = 0; dt < 4; ++dt) {
                s16x8 vb = *(const s16x8*)(&v_t[(dt * 16 + fr) * VP + kc * 32 + ks * 8]);
                o[dt] = __builtin_amdgcn_mfma_f32_16x16x32_bf16(pa, vb, o[dt], 0, 0, 0);
            }
        }

#pragma unroll
        for (int dt = 0; dt < 4; ++dt) {
            const int d = h * 64 + dt * 16 + fr;
#pragma unroll
            for (int i = 0; i < 4; ++i) {
                const int q = qt * 16 + ks * 4 + i;
                if (q < 150)
                    o_att[((size_t)((b0 + bl) * 150 + q)) * 512 + d] = f2bf(o[dt][i] * inv[i]);
            }
        }
    }
}

// ---------------------------------------------------------------------------
// osum[b,d] = sum_m o_att[b,m,d]
// ---------------------------------------------------------------------------
__global__ __launch_bounds__(512) void osum_kernel(
    const unsigned short* __restrict__ o_att, unsigned short* __restrict__ osum)
{
    const int b = blockIdx.x, tid = threadIdx.x;
    float s = 0.f;
    const unsigned short* p = o_att + (size_t)b * 150 * 512 + tid;
    for (int mm = 0; mm < 150; ++mm) s += bf2f(p[(size_t)mm * 512]);
    osum[(size_t)b * 512 + tid] = f2bf(s);
}

// ---------------------------------------------------------------------------
extern "C" void kernel_launch(void* const* d_in, const int* in_sizes, int n_in,
                              void* d_out, int out_size, void* d_ws, size_t ws_size,
                              hipStream_t stream)
{
    (void)in_sizes; (void)n_in; (void)out_size; (void)ws_size;

    const int*   x          = (const int*)d_in[0];
    const float* emb        = (const float*)d_in[1];
    const float* W1         = (const float*)d_in[2];
    const float* b1         = (const float*)d_in[3];
    const float* ln1_g      = (const float*)d_in[4];
    const float* ln1_b      = (const float*)d_in[5];
    const float* W2         = (const float*)d_in[6];
    const float* b2         = (const float*)d_in[7];
    const float* dbias      = (const float*)d_in[8];
    const float* in_proj_w  = (const float*)d_in[9];
    const float* in_proj_b  = (const float*)d_in[10];
    const float* out_proj_w = (const float*)d_in[11];
    const float* out_proj_b = (const float*)d_in[12];
    const float* norm_g     = (const float*)d_in[13];
    const float* norm_b     = (const float*)d_in[14];
    const float* dec_w1     = (const float*)d_in[15];
    const float* dec_b1     = (const float*)d_in[16];
    const float* dec_w2     = (const float*)d_in[17];
    const float* dec_b2     = (const float*)d_in[18];

    char* ws = (char*)d_ws;
    unsigned short* e_bf  = (unsigned short*)(ws + 0x0);        // [256,512] bf16
    unsigned short* osum  = (unsigned short*)(ws + 0x40000);
    unsigned short* att1  = (unsigned short*)(ws + 0x80000);
    unsigned short* agg   = (unsigned short*)(ws + 0xC0000);
    unsigned short* dec1  = (unsigned short*)(ws + 0x100000);
    unsigned short* h1    = (unsigned short*)(ws + 0x200000);   // [B,M,D] 37.5MB (later o_att)
    unsigned short* mo    = (unsigned short*)(ws + 0x2800000);  // [B,M,D] 37.5MB
    unsigned short* qkvb  = (unsigned short*)(ws + 0x4E00000);  // [64,M,3D] 28.1MB chunk
    unsigned short* o_att = h1;

    // 1) embedding mean -> e [256,512]
    embed_kernel<<<256, 512, 0, stream>>>(x, emb, e_bf);

    // 2) G1: h1[b,m,:] = e[b,:] @ W1[m]^T + b1[m]   (A shared across modes)
    gemm256_kernel<false><<<dim3(4, 150), 512, 0, stream>>>(
        e_bf, W1, b1, nullptr, 1.f, h1,
        512, 38400, (size_t)0, 512, (size_t)512 * 512, 512, 512, 76800);

    // 3) LN(ln1_g, ln1_b) + ReLU, in-place on h1
    ln_kernel<true><<<38400, 256, 0, stream>>>(h1, ln1_g, ln1_b, h1, 150);

    // 4) G2: mo[b,m,:] = h1[b,m,:] @ W2[m]^T + b2[m] + dbias[m]
    gemm256_kernel<false><<<dim3(4, 150), 512, 0, stream>>>(
        h1, W2, b2, dbias, 1.f, mo,
        512, 38400, (size_t)512, 76800, (size_t)512 * 512, 512, 512, 76800);

    // 5) per 64-batch chunk: qkv = mo_chunk @ in_proj_w^T + b, then attention
    for (int c = 0; c < 4; ++c) {
        gemm256_kernel<false><<<dim3(12, 38), 512, 0, stream>>>(
            mo + (size_t)c * 64 * 76800, in_proj_w, in_proj_b, nullptr, 1.f, qkvb,
            512, 9600, (size_t)256 * 512, 512, (size_t)0, 0, (size_t)256 * 1536, 1536);
        attn_mfma_kernel<<<512, 256, 0, stream>>>(qkvb, o_att, c * 64);
    }

    // 6) osum[b,:] = sum_m o_att[b,m,:]
    osum_kernel<<<256, 512, 0, stream>>>(o_att, osum);

    // 7) attended_sum = osum @ out_proj_w^T + 150*out_proj_b
    gemm256_kernel<false><<<dim3(4, 1), 512, 0, stream>>>(
        osum, out_proj_w, out_proj_b, nullptr, 150.f, att1,
        512, 256, (size_t)0, 512, (size_t)0, 0, 0, 512);

    // 8) agg = LN(attended_sum; norm_g, norm_b)
    ln_kernel<false><<<256, 256, 0, stream>>>(att1, norm_g, norm_b, agg, 1);

    // 9) dec1 = ReLU(agg @ dec_w1^T + dec_b1)   [256,256]
    gemm256_kernel<true><<<dim3(2, 1), 512, 0, stream>>>(
        agg, dec_w1, dec_b1, nullptr, 1.f, dec1,
        512, 256, (size_t)0, 512, (size_t)0, 0, 0, 256);

    // 10) out = dec1 @ dec_w2^T + dec_b2   [256,10000] f32 (K=256, N%128!=0)
    gemm_bt_kernel<false, true><<<dim3(157, 4, 1), 256, 0, stream>>>(
        dec1, dec_w2, dec_b2, nullptr, 1.f, d_out,
        10000, 256, (size_t)0, 256, (size_t)0, 0, 0, 10000);
}